// Round 11
// baseline (148.877 us; speedup 1.0000x reference)
//
#include <hip/hip_runtime.h>

// Chamfer loss: B=32, N=M=2048, D=3, fp32 in, scalar fp32 out.
// loss = sum_b [ sum_m min_n d2 + sum_n min_m d2 ] / B
//
// v10 = v8 + scan amplification probe (REPS=12). Purpose: measurement.
// Three structural changes (v7 tail, v8 occupancy, v9 work-split) all moved
// dur_us by <2us; the kernel has never been visible in top-5 rocprof rows
// (fill dispatches saturate it), so scan time / VGPR / pipe counters are
// unknown. This round: run the scan loop 12x with rotated tile order
// (idempotent: min over the same tile set; rotation defeats CSE/LICM).
//  - dur_us = floor(~70) + 11 * T_scan  -> direct scalar readout.
//  - kernel dur ~12*T_scan >= 48us -> forced into top-5 -> VGPR_Count,
//    MfmaUtil, VALUBusy, SQ_LDS_BANK_CONFLICT finally visible.
// Output is bit-identical to v8 (scan repetition only recomputes the same
// running min; all reps read the same LDS B-frags).
//
// Score math (validated absmax=0 in v5-v9): s[q][p] = h_p - q.p via
// 32x32x16 bf16 MFMA, split bf16:
//   A_k = [-qhx,-qhy,-qhz, -qhx,-qhy,-qhz, -qlx,-qly | -qlz, 1, 1, 0...]
//   B_k = [ phx, phy, phz,  plx, ply, plz,  phx, phy |  phz, hh, hl, 0...]
// d2 = max(0, 2*s_min + |q|^2) per row (min is monotone). Same lane->k map
// on both operands -> HW k-permutation cancels. C/D: col=lane&31,
// row=(reg&3)+8*(reg>>2)+4*(lane>>5), HW-verified (m74/m101).

typedef __attribute__((ext_vector_type(8)))  short bf16x8;
typedef __attribute__((ext_vector_type(16))) float f32x16;
typedef __attribute__((ext_vector_type(4)))  unsigned int u32x4;

constexpr int B_SZ    = 32;
constexpr int NPTS    = 2048;
constexpr int BLOCK   = 512;               // 8 waves
constexpr int STRIPES = 8;                 // 2048 rows / 256 rows-per-block
constexpr int CT      = NPTS / 32;         // 64 col-tiles

__device__ __forceinline__ unsigned short f2bf(float f) {   // RNE f32->bf16
    unsigned int u = __float_as_uint(f);
    u += 0x7FFFu + ((u >> 16) & 1u);
    return (unsigned short)(u >> 16);
}
__device__ __forceinline__ float bf2f(unsigned short h) {
    return __uint_as_float(((unsigned int)h) << 16);
}
__device__ __forceinline__ unsigned int pk(unsigned short lo, unsigned short hi) {
    return (unsigned int)lo | ((unsigned int)hi << 16);
}

template <int REPS>
__global__ __launch_bounds__(BLOCK, 4)     // cap VGPR at 128 -> 4 waves/SIMD
void chamfer_fused(const float* __restrict__ x, const float* __restrict__ y,
                   float* __restrict__ out) {
    __shared__ u32x4 blds[CT * 64];        // 64 KB B-frags; aliased as colm
    __shared__ float wsum[BLOCK / 64];

    const int bid    = blockIdx.x;
    const int stripe = bid & (STRIPES - 1);
    const int b      = (bid >> 3) & 31;
    const int dir    = bid >> 8;

    const float* q = ((dir == 0) ? x : y) + (size_t)b * NPTS * 3;  // queries
    const float* p = ((dir == 0) ? y : x) + (size_t)b * NPTS * 3;  // points

    // ---- Pack B-fragments for the whole opposing cloud into LDS.
    for (int pi = threadIdx.x; pi < NPTS; pi += BLOCK) {
        const float vx = p[pi * 3 + 0], vy = p[pi * 3 + 1], vz = p[pi * 3 + 2];
        const unsigned short hx = f2bf(vx), hy = f2bf(vy), hz = f2bf(vz);
        const unsigned short lx = f2bf(vx - bf2f(hx));
        const unsigned short ly = f2bf(vy - bf2f(hy));
        const unsigned short lz = f2bf(vz - bf2f(hz));
        const float h = 0.5f * fmaf(vx, vx, fmaf(vy, vy, vz * vz));
        const unsigned short hh = f2bf(h);
        const unsigned short hl = f2bf(h - bf2f(hh));
        const int ct = pi >> 5, col = pi & 31;
        u32x4 g0 = {pk(hx, hy), pk(hz, lx), pk(ly, lz), pk(hx, hy)};
        u32x4 g1 = {pk(hz, hh), pk(hl, 0), 0u, 0u};
        blds[ct * 64 + col]      = g0;     // k0..7
        blds[ct * 64 + 32 + col] = g1;     // k8..15
    }

    // ---- Pack this wave's A-fragment (1 row-tile = 32 rows per wave).
    const int w    = threadIdx.x >> 6;     // wave 0..7
    const int lane = threadIdx.x & 63;
    const int g    = lane >> 5;            // k-half
    const int r32  = lane & 31;            // row (A) / col (C) within tile
    const int row  = stripe * 256 + w * 32 + r32;
    bf16x8 afrag;
    {
        const float vx = q[row * 3 + 0], vy = q[row * 3 + 1], vz = q[row * 3 + 2];
        const unsigned short hx = f2bf(vx) ^ 0x8000, hy = f2bf(vy) ^ 0x8000,
                             hz = f2bf(vz) ^ 0x8000;
        const unsigned short lx = f2bf(vx - bf2f(hx ^ 0x8000)) ^ 0x8000;
        const unsigned short ly = f2bf(vy - bf2f(hy ^ 0x8000)) ^ 0x8000;
        const unsigned short lz = f2bf(vz - bf2f(hz ^ 0x8000)) ^ 0x8000;
        u32x4 fr;
        if (g == 0)
            fr = (u32x4){pk(hx, hy), pk(hz, hx), pk(hy, hz), pk(lx, ly)};
        else
            fr = (u32x4){pk(lz, 0x3F80), pk(0x3F80, 0), 0u, 0u};
        afrag = __builtin_bit_cast(bf16x8, fr);
    }
    __syncthreads();

    // ---- Scan, repeated REPS times with rotated tile order (same min set,
    // rep-dependent addresses -> compiler cannot CSE across reps).
    const f32x16 z = {0.f,0.f,0.f,0.f,0.f,0.f,0.f,0.f,
                      0.f,0.f,0.f,0.f,0.f,0.f,0.f,0.f};
    f32x16 rmin;
    #pragma unroll
    for (int j = 0; j < 16; ++j) rmin[j] = 3.0e38f;

    for (int rep = 0; rep < REPS; ++rep) {
        #pragma unroll 2
        for (int i = 0; i < CT; i += 2) {
            const int ct = (i + rep * 2) & (CT - 1);   // even, rotated
            const bf16x8 b0 = __builtin_bit_cast(bf16x8, blds[ct * 64 + lane]);
            const bf16x8 b1 = __builtin_bit_cast(bf16x8, blds[ct * 64 + 64 + lane]);
            __builtin_amdgcn_s_setprio(1);
            f32x16 a0 = __builtin_amdgcn_mfma_f32_32x32x16_bf16(afrag, b0, z, 0, 0, 0);
            f32x16 a1 = __builtin_amdgcn_mfma_f32_32x32x16_bf16(afrag, b1, z, 0, 0, 0);
            __builtin_amdgcn_s_setprio(0);
            #pragma unroll
            for (int j = 0; j < 16; ++j)   // v_min3_f32
                rmin[j] = fminf(fminf(a0[j], a1[j]), rmin[j]);
        }
    }

    // ---- Transpose-reduce over cols (XOR-rotate swizzle, conflict-free).
    __syncthreads();                        // all B-frag reads done
    float* colm = (float*)blds;
    #pragma unroll
    for (int j = 0; j < 16; ++j) {
        const int lr = w * 32 + (j & 3) + 8 * (j >> 2) + 4 * g;  // local row
        colm[lr * 32 + ((r32 + lr) & 31)] = rmin[j];
    }
    __syncthreads();

    // ---- Threads 0..255: min over 32 col-partials (fmin tree) + d2.
    const int t = threadIdx.x;
    float s = 0.0f;
    if (t < 256) {
        float v[32];
        #pragma unroll
        for (int k = 0; k < 32; ++k) v[k] = colm[t * 32 + ((k + t) & 31)];
        #pragma unroll
        for (int st = 16; st > 0; st >>= 1)
            #pragma unroll
            for (int i = 0; i < st; ++i) v[i] = fminf(v[i], v[i + st]);
        const int grow = stripe * 256 + t;
        const float qx = q[grow * 3 + 0], qy = q[grow * 3 + 1], qz = q[grow * 3 + 2];
        const float q2 = fmaf(qx, qx, fmaf(qy, qy, qz * qz));
        s = fmaxf(0.0f, fmaf(2.0f, v[0], q2));
    }

    // ---- Block sum, one atomic.
    #pragma unroll
    for (int off = 32; off > 0; off >>= 1) s += __shfl_down(s, off, 64);
    if ((t & 63) == 0) wsum[t >> 6] = s;
    __syncthreads();
    if (t == 0) {
        float tt = 0.f;
        #pragma unroll
        for (int wv = 0; wv < BLOCK / 64; ++wv) tt += wsum[wv];
        atomicAdd(out, tt * (1.0f / B_SZ));
    }
}

extern "C" void kernel_launch(void* const* d_in, const int* in_sizes, int n_in,
                              void* d_out, int out_size, void* d_ws, size_t ws_size,
                              hipStream_t stream) {
    const float* x = (const float*)d_in[0];
    const float* y = (const float*)d_in[1];
    float* out = (float*)d_out;

    hipMemsetAsync(out, 0, sizeof(float) * out_size, stream);
    chamfer_fused<12><<<2 * B_SZ * STRIPES, BLOCK, 0, stream>>>(x, y, out);
}

// Round 12
// 70.458 us; speedup vs baseline: 2.1130x; 2.1130x over previous
//
#include <hip/hip_runtime.h>

// Chamfer loss: B=32, N=M=2048, D=3, fp32 in, scalar fp32 out.
// loss = sum_b [ sum_m min_n d2 + sum_n min_m d2 ] / B
//
// v11 = v8 with the scan software-pipelined (depth 2) + fully unrolled.
// Round-11 probe (REPS=12) measured: T_scan = 7.2us/pass, kernel = 22us,
// harness floor = 48us. MFMA 32x32x16 costs 32 cyc/SIMD (m119 recalib), so
// scan matrix demand = 3.4us; measured 7.2 = matrix + VALU SUMMED -> the
// min3s depend on the just-issued MFMA pair, stalling each wave through
// MFMA latency (pipes alternate instead of overlap).
// Fix: ping-pong two MFMA result pairs; min3 consumes the PREVIOUS pair
// (results long ready) while the current pair occupies the matrix pipe.
// Full unroll makes every ds_read_b128 base+imm (zero addr VALU) and all
// f32x16 names static (no scratch, rule #20). setprio dropped (lockstep
// GEMM regime: measured slightly negative, m190).
//
// Score math (validated absmax=0 in v5-v10): s[q][p] = h_p - q.p via
// 32x32x16 bf16 MFMA, split bf16:
//   A_k = [-qhx,-qhy,-qhz, -qhx,-qhy,-qhz, -qlx,-qly | -qlz, 1, 1, 0...]
//   B_k = [ phx, phy, phz,  plx, ply, plz,  phx, phy |  phz, hh, hl, 0...]
// d2 = max(0, 2*s_min + |q|^2) per row (min is monotone). Same lane->k map
// on both operands -> HW k-permutation cancels. C/D: col=lane&31,
// row=(reg&3)+8*(reg>>2)+4*(lane>>5), HW-verified (m74/m101).
//
// Grid 512 = [dir(2)][batch(32)][stripe(8)]; 8 waves x 32 rows; B-frags for
// the whole opposing cloud in 64KB LDS; 2 blocks/CU. Tail: XOR-rotate-
// swizzled 256x32 transpose-reduce aliased on the dead B-frag buffer.

typedef __attribute__((ext_vector_type(8)))  short bf16x8;
typedef __attribute__((ext_vector_type(16))) float f32x16;
typedef __attribute__((ext_vector_type(4)))  unsigned int u32x4;

constexpr int B_SZ    = 32;
constexpr int NPTS    = 2048;
constexpr int BLOCK   = 512;               // 8 waves
constexpr int STRIPES = 8;                 // 2048 rows / 256 rows-per-block
constexpr int CT      = NPTS / 32;         // 64 col-tiles

__device__ __forceinline__ unsigned short f2bf(float f) {   // RNE f32->bf16
    unsigned int u = __float_as_uint(f);
    u += 0x7FFFu + ((u >> 16) & 1u);
    return (unsigned short)(u >> 16);
}
__device__ __forceinline__ float bf2f(unsigned short h) {
    return __uint_as_float(((unsigned int)h) << 16);
}
__device__ __forceinline__ unsigned int pk(unsigned short lo, unsigned short hi) {
    return (unsigned int)lo | ((unsigned int)hi << 16);
}

__global__ __launch_bounds__(BLOCK, 4)     // cap VGPR at 128 -> 4 waves/SIMD
void chamfer_fused(const float* __restrict__ x, const float* __restrict__ y,
                   float* __restrict__ out) {
    __shared__ u32x4 blds[CT * 64];        // 64 KB B-frags; aliased as colm
    __shared__ float wsum[BLOCK / 64];

    const int bid    = blockIdx.x;
    const int stripe = bid & (STRIPES - 1);
    const int b      = (bid >> 3) & 31;
    const int dir    = bid >> 8;

    const float* q = ((dir == 0) ? x : y) + (size_t)b * NPTS * 3;  // queries
    const float* p = ((dir == 0) ? y : x) + (size_t)b * NPTS * 3;  // points

    // ---- Pack B-fragments for the whole opposing cloud into LDS.
    for (int pi = threadIdx.x; pi < NPTS; pi += BLOCK) {
        const float vx = p[pi * 3 + 0], vy = p[pi * 3 + 1], vz = p[pi * 3 + 2];
        const unsigned short hx = f2bf(vx), hy = f2bf(vy), hz = f2bf(vz);
        const unsigned short lx = f2bf(vx - bf2f(hx));
        const unsigned short ly = f2bf(vy - bf2f(hy));
        const unsigned short lz = f2bf(vz - bf2f(hz));
        const float h = 0.5f * fmaf(vx, vx, fmaf(vy, vy, vz * vz));
        const unsigned short hh = f2bf(h);
        const unsigned short hl = f2bf(h - bf2f(hh));
        const int ct = pi >> 5, col = pi & 31;
        u32x4 g0 = {pk(hx, hy), pk(hz, lx), pk(ly, lz), pk(hx, hy)};
        u32x4 g1 = {pk(hz, hh), pk(hl, 0), 0u, 0u};
        blds[ct * 64 + col]      = g0;     // k0..7
        blds[ct * 64 + 32 + col] = g1;     // k8..15
    }

    // ---- Pack this wave's A-fragment (1 row-tile = 32 rows per wave).
    const int w    = threadIdx.x >> 6;     // wave 0..7
    const int lane = threadIdx.x & 63;
    const int g    = lane >> 5;            // k-half
    const int r32  = lane & 31;            // row (A) / col (C) within tile
    const int row  = stripe * 256 + w * 32 + r32;
    bf16x8 afrag;
    {
        const float vx = q[row * 3 + 0], vy = q[row * 3 + 1], vz = q[row * 3 + 2];
        const unsigned short hx = f2bf(vx) ^ 0x8000, hy = f2bf(vy) ^ 0x8000,
                             hz = f2bf(vz) ^ 0x8000;
        const unsigned short lx = f2bf(vx - bf2f(hx ^ 0x8000)) ^ 0x8000;
        const unsigned short ly = f2bf(vy - bf2f(hy ^ 0x8000)) ^ 0x8000;
        const unsigned short lz = f2bf(vz - bf2f(hz ^ 0x8000)) ^ 0x8000;
        u32x4 fr;
        if (g == 0)
            fr = (u32x4){pk(hx, hy), pk(hz, hx), pk(hy, hz), pk(lx, ly)};
        else
            fr = (u32x4){pk(lz, 0x3F80), pk(0x3F80, 0), 0u, 0u};
        afrag = __builtin_bit_cast(bf16x8, fr);
    }
    __syncthreads();

    // ---- Scan: 64 tiles, fully unrolled, 2-deep MFMA ping-pong pipeline.
    const f32x16 z = {0.f,0.f,0.f,0.f,0.f,0.f,0.f,0.f,
                      0.f,0.f,0.f,0.f,0.f,0.f,0.f,0.f};
    f32x16 rmin;
    #pragma unroll
    for (int j = 0; j < 16; ++j) rmin[j] = 3.0e38f;

    // prologue: tiles 0,1 in flight
    bf16x8 t0 = __builtin_bit_cast(bf16x8, blds[0 * 64 + lane]);
    bf16x8 t1 = __builtin_bit_cast(bf16x8, blds[1 * 64 + lane]);
    f32x16 pA = __builtin_amdgcn_mfma_f32_32x32x16_bf16(afrag, t0, z, 0, 0, 0);
    f32x16 pB = __builtin_amdgcn_mfma_f32_32x32x16_bf16(afrag, t1, z, 0, 0, 0);

    // 15 bodies x 4 tiles: tiles 2..61. All LDS indices compile-time.
    #pragma unroll
    for (int it = 0; it < 15; ++it) {
        const int c = 2 + it * 4;
        bf16x8 u0 = __builtin_bit_cast(bf16x8, blds[(c + 0) * 64 + lane]);
        bf16x8 u1 = __builtin_bit_cast(bf16x8, blds[(c + 1) * 64 + lane]);
        f32x16 cA = __builtin_amdgcn_mfma_f32_32x32x16_bf16(afrag, u0, z, 0, 0, 0);
        f32x16 cB = __builtin_amdgcn_mfma_f32_32x32x16_bf16(afrag, u1, z, 0, 0, 0);
        #pragma unroll
        for (int j = 0; j < 16; ++j)       // consume PREVIOUS pair (ready)
            rmin[j] = fminf(fminf(pA[j], pB[j]), rmin[j]);
        bf16x8 u2 = __builtin_bit_cast(bf16x8, blds[(c + 2) * 64 + lane]);
        bf16x8 u3 = __builtin_bit_cast(bf16x8, blds[(c + 3) * 64 + lane]);
        pA = __builtin_amdgcn_mfma_f32_32x32x16_bf16(afrag, u2, z, 0, 0, 0);
        pB = __builtin_amdgcn_mfma_f32_32x32x16_bf16(afrag, u3, z, 0, 0, 0);
        #pragma unroll
        for (int j = 0; j < 16; ++j)       // consume the other pair
            rmin[j] = fminf(fminf(cA[j], cB[j]), rmin[j]);
    }

    // epilogue: tiles 62,63 + drain both pairs
    {
        bf16x8 v0 = __builtin_bit_cast(bf16x8, blds[62 * 64 + lane]);
        bf16x8 v1 = __builtin_bit_cast(bf16x8, blds[63 * 64 + lane]);
        f32x16 eA = __builtin_amdgcn_mfma_f32_32x32x16_bf16(afrag, v0, z, 0, 0, 0);
        f32x16 eB = __builtin_amdgcn_mfma_f32_32x32x16_bf16(afrag, v1, z, 0, 0, 0);
        #pragma unroll
        for (int j = 0; j < 16; ++j)
            rmin[j] = fminf(fminf(pA[j], pB[j]), rmin[j]);
        #pragma unroll
        for (int j = 0; j < 16; ++j)
            rmin[j] = fminf(fminf(eA[j], eB[j]), rmin[j]);
    }

    // ---- Transpose-reduce over cols (XOR-rotate swizzle, conflict-free).
    __syncthreads();                        // all B-frag reads done
    float* colm = (float*)blds;
    #pragma unroll
    for (int j = 0; j < 16; ++j) {
        const int lr = w * 32 + (j & 3) + 8 * (j >> 2) + 4 * g;  // local row
        colm[lr * 32 + ((r32 + lr) & 31)] = rmin[j];
    }
    __syncthreads();

    // ---- Threads 0..255: min over 32 col-partials (fmin tree) + d2.
    const int t = threadIdx.x;
    float s = 0.0f;
    if (t < 256) {
        float v[32];
        #pragma unroll
        for (int k = 0; k < 32; ++k) v[k] = colm[t * 32 + ((k + t) & 31)];
        #pragma unroll
        for (int st = 16; st > 0; st >>= 1)
            #pragma unroll
            for (int i = 0; i < st; ++i) v[i] = fminf(v[i], v[i + st]);
        const int grow = stripe * 256 + t;
        const float qx = q[grow * 3 + 0], qy = q[grow * 3 + 1], qz = q[grow * 3 + 2];
        const float q2 = fmaf(qx, qx, fmaf(qy, qy, qz * qz));
        s = fmaxf(0.0f, fmaf(2.0f, v[0], q2));
    }

    // ---- Block sum, one atomic.
    #pragma unroll
    for (int off = 32; off > 0; off >>= 1) s += __shfl_down(s, off, 64);
    if ((t & 63) == 0) wsum[t >> 6] = s;
    __syncthreads();
    if (t == 0) {
        float tt = 0.f;
        #pragma unroll
        for (int wv = 0; wv < BLOCK / 64; ++wv) tt += wsum[wv];
        atomicAdd(out, tt * (1.0f / B_SZ));
    }
}

extern "C" void kernel_launch(void* const* d_in, const int* in_sizes, int n_in,
                              void* d_out, int out_size, void* d_ws, size_t ws_size,
                              hipStream_t stream) {
    const float* x = (const float*)d_in[0];
    const float* y = (const float*)d_in[1];
    float* out = (float*)d_out;

    hipMemsetAsync(out, 0, sizeof(float) * out_size, stream);
    chamfer_fused<<<2 * B_SZ * STRIPES, BLOCK, 0, stream>>>(x, y, out);
}